// Round 1
// 242.587 us; speedup vs baseline: 1.1933x; 1.1933x over previous
//
#include <hip/hip_runtime.h>

#define N_NODES 50000
#define N_EDGES 600000
#define D 128
#define NLAYERS 3
#define CSR_CAP (N_EDGES + 3 * N_NODES)   // padded CSR worst case (pad-to-4)

typedef __attribute__((ext_vector_type(8))) short short8;
typedef __attribute__((ext_vector_type(4))) float floatx4;

__device__ __forceinline__ float bf_lo(unsigned u) { return __uint_as_float(u << 16); }
__device__ __forceinline__ float bf_hi(unsigned u) { return __uint_as_float(u & 0xffff0000u); }
__device__ __forceinline__ unsigned short f2bf(float f) {
    unsigned u = __float_as_uint(f);
    return (unsigned short)((u + 0x7fffu + ((u >> 16) & 1u)) >> 16);
}

// ---------------- merged: x->bf16, WtF build, zero-init (incl. sentinel rows) --------
// section A: [0, CVT_A)           one float4 of x -> ushort4 of xb
// section B: [CVT_A, +CVT_B)      one bf16 element of WtF (MFMA B-fragment order)
// section C: [+CVT_B, +N_NODES)   zero deg/cursor; j==0 zeroes counter; j<D zeroes pad rows

#define CVT_A (N_NODES * D / 4)              // 1,600,000
#define CVT_B (NLAYERS * D * 256)            // 98,304
#define CVT_TOTAL (CVT_A + CVT_B + N_NODES)

__global__ void cvt_init_kernel(const float* __restrict__ x, const float* __restrict__ Wl,
                                const float* __restrict__ Wr,
                                unsigned short* __restrict__ xb,
                                unsigned short* __restrict__ hb1,
                                unsigned short* __restrict__ hb2,
                                unsigned short* __restrict__ WtF,
                                int* __restrict__ deg, int* __restrict__ cursor,
                                int* __restrict__ counter) {
    int i = blockIdx.x * blockDim.x + threadIdx.x;
    if (i < CVT_A) {
        float4 v = ((const float4*)x)[i];
        ushort4 o;
        o.x = f2bf(v.x); o.y = f2bf(v.y); o.z = f2bf(v.z); o.w = f2bf(v.w);
        ((ushort4*)xb)[i] = o;
    } else if (i < CVT_A + CVT_B) {
        int t = i - CVT_A;
        int l = t >> 15;
        int r = t & 32767;
        int f = r >> 3;
        int ii = r & 7;
        int jkt = f >> 6;
        int lane = f & 63;
        int j = jkt >> 3;
        int kt = jkt & 7;
        int half = lane & 15;
        int quad = lane >> 4;
        int n = j * 16 + half;
        int k = kt * 32 + quad * 8 + ii;
        float v = (k < D) ? Wl[(size_t)l * D * D + (size_t)k * D + n]
                          : Wr[(size_t)l * D * D + (size_t)(k - D) * D + n];
        WtF[t] = f2bf(v);
    } else if (i < CVT_TOTAL) {
        int j = i - (CVT_A + CVT_B);
        deg[j] = 0;
        cursor[j] = 0;
        if (j == 0) counter[0] = 0;
        if (j < D) {                         // zero the sentinel row N_NODES
            xb[(size_t)N_NODES * D + j] = 0;
            hb1[(size_t)N_NODES * D + j] = 0;
            hb2[(size_t)N_NODES * D + j] = 0;
        }
    }
}

// ---------------- CSR build ----------------

__global__ void hist_kernel(const int* __restrict__ dst, int* __restrict__ deg) {
    int e = blockIdx.x * blockDim.x + threadIdx.x;
    if (e < N_EDGES) atomicAdd(&deg[dst[e]], 1);
}

// row_start via per-wave scan of PADDED sizes + one atomicAdd per wave; writes sentinel pads
__global__ void alloc_kernel(const int* __restrict__ deg, int* __restrict__ counter,
                             int* __restrict__ row_start, float* __restrict__ inv_deg,
                             int* __restrict__ csr_src) {
    int i = blockIdx.x * blockDim.x + threadIdx.x;
    int lane = threadIdx.x & 63;
    int d = (i < N_NODES) ? deg[i] : 0;
    int pd = (d + 3) & ~3;
    int v = pd;
    #pragma unroll
    for (int off = 1; off < 64; off <<= 1) {
        int t = __shfl_up(v, off, 64);
        if (lane >= off) v += t;
    }
    int total = __shfl(v, 63, 64);
    int base = 0;
    if (lane == 63) base = atomicAdd(counter, total);
    base = __shfl(base, 63, 64);
    if (i < N_NODES) {
        int rs = base + v - pd;
        row_start[i] = rs;
        inv_deg[i] = 1.0f / fmaxf((float)d, 1.0f);
        for (int k = d; k < pd; k++) csr_src[rs + k] = N_NODES;   // sentinel pads
    }
}

__global__ void fill_kernel(const int* __restrict__ src, const int* __restrict__ dst,
                            const int* __restrict__ row_start, int* __restrict__ cursor,
                            int* __restrict__ csr_src) {
    int e = blockIdx.x * blockDim.x + threadIdx.x;
    if (e < N_EDGES) {
        int d_ = dst[e];
        int pos = atomicAdd(&cursor[d_], 1);
        csr_src[row_start[d_] + pos] = src[e];
    }
}

// ---------------- fused layer: agg(mean gather) -> LDS -> MFMA GEMM -> relu -> out ----
// 256 threads = 4 waves per 32-node tile.
// Phase 1: gather mean-agg (chunks 0..15) and stage own hin rows (chunks 16..31) into
//          XOR-swizzled A tile a_s[32][256] bf16 (physical 16B-chunk = logical ^ (row&7)).
// Phase 2: each wave computes 2 column-fragments (32 cols) of the 32x128 output, K=256.
// Epilogue: middle layers stage to c_s + coalesced uint4 store; last layer fuses the
//           W_out readout with an LDS cross-wave reduction.

template <bool LAST>
__global__ __launch_bounds__(256) void fused_layer_kernel(
    const unsigned short* __restrict__ hin,
    const int* __restrict__ row_start, const int* __restrict__ deg,
    const int* __restrict__ csr_src, const float* __restrict__ inv_deg,
    const unsigned short* __restrict__ WtF, const float* __restrict__ bias,
    unsigned short* __restrict__ hout,
    const float* __restrict__ Wout, const float* __restrict__ bout,
    float* __restrict__ out) {
    __shared__ unsigned short a_s[32 * 256];   // swizzled A tile: [row][256] bf16
    __shared__ unsigned short c_s[32][136];    // output staging (middle layers) / red (last)

    int m0 = blockIdx.x * 32;
    int tid = threadIdx.x;

    // ---- phase 1a: stage hin rows m0..m0+31 (logical chunks 16..31)
    #pragma unroll
    for (int it = 0; it < 2; ++it) {
        int t = it * 256 + tid;          // 0..511
        int rl = t >> 4;                 // 0..31
        int c = t & 15;                  // 0..15
        int row = min(m0 + rl, N_NODES - 1);
        uint4 v = *((const uint4*)(hin + (size_t)row * D + c * 8));
        int chunk = (16 + c) ^ (rl & 7);
        *((uint4*)&a_s[rl * 256 + chunk * 8]) = v;
    }

    // ---- phase 1b: mean aggregate, 2 nodes per 16-lane group (logical chunks 0..15)
    {
        int grp = tid >> 4;
        int q = tid & 15;
        for (int half_ = 0; half_ < 2; ++half_) {
            int nl = grp + half_ * 16;
            int node = m0 + nl;
            float a[8] = {0.f, 0.f, 0.f, 0.f, 0.f, 0.f, 0.f, 0.f};
            float b[8] = {0.f, 0.f, 0.f, 0.f, 0.f, 0.f, 0.f, 0.f};
            float w = 0.f;
            if (node < N_NODES) {
                int d = deg[node];
                int pd = (d + 3) & ~3;
                int beg = row_start[node];
                for (int e = beg; e < beg + pd; e += 16) {
                    int cnt = min(beg + pd - e, 16);            // multiple of 4
                    int idx = csr_src[e + min(q, cnt - 1)];     // coalesced index preload
                    for (int j = 0; j < cnt; j += 4) {
                        int s0 = __shfl(idx, j + 0, 16);
                        int s1 = __shfl(idx, j + 1, 16);
                        int s2 = __shfl(idx, j + 2, 16);
                        int s3 = __shfl(idx, j + 3, 16);
                        uint4 v0 = *((const uint4*)(hin + (size_t)s0 * D + q * 8));
                        uint4 v1 = *((const uint4*)(hin + (size_t)s1 * D + q * 8));
                        uint4 v2 = *((const uint4*)(hin + (size_t)s2 * D + q * 8));
                        uint4 v3 = *((const uint4*)(hin + (size_t)s3 * D + q * 8));
                        a[0] += bf_lo(v0.x); a[1] += bf_hi(v0.x);
                        a[2] += bf_lo(v0.y); a[3] += bf_hi(v0.y);
                        a[4] += bf_lo(v0.z); a[5] += bf_hi(v0.z);
                        a[6] += bf_lo(v0.w); a[7] += bf_hi(v0.w);
                        b[0] += bf_lo(v1.x); b[1] += bf_hi(v1.x);
                        b[2] += bf_lo(v1.y); b[3] += bf_hi(v1.y);
                        b[4] += bf_lo(v1.z); b[5] += bf_hi(v1.z);
                        b[6] += bf_lo(v1.w); b[7] += bf_hi(v1.w);
                        a[0] += bf_lo(v2.x); a[1] += bf_hi(v2.x);
                        a[2] += bf_lo(v2.y); a[3] += bf_hi(v2.y);
                        a[4] += bf_lo(v2.z); a[5] += bf_hi(v2.z);
                        a[6] += bf_lo(v2.w); a[7] += bf_hi(v2.w);
                        b[0] += bf_lo(v3.x); b[1] += bf_hi(v3.x);
                        b[2] += bf_lo(v3.y); b[3] += bf_hi(v3.y);
                        b[4] += bf_lo(v3.z); b[5] += bf_hi(v3.z);
                        b[6] += bf_lo(v3.w); b[7] += bf_hi(v3.w);
                    }
                }
                w = inv_deg[node];
            }
            uint4 o;
            o.x = (unsigned)f2bf((a[0] + b[0]) * w) | ((unsigned)f2bf((a[1] + b[1]) * w) << 16);
            o.y = (unsigned)f2bf((a[2] + b[2]) * w) | ((unsigned)f2bf((a[3] + b[3]) * w) << 16);
            o.z = (unsigned)f2bf((a[4] + b[4]) * w) | ((unsigned)f2bf((a[5] + b[5]) * w) << 16);
            o.w = (unsigned)f2bf((a[6] + b[6]) * w) | ((unsigned)f2bf((a[7] + b[7]) * w) << 16);
            int chunk = q ^ (nl & 7);
            *((uint4*)&a_s[nl * 256 + chunk * 8]) = o;
        }
    }
    __syncthreads();

    // ---- phase 2: MFMA. wave wv owns columns [wv*32, wv*32+32)
    int wv = tid >> 6;
    int lane = tid & 63;
    int half = lane & 15;
    int quad = lane >> 4;

    floatx4 acc[2][2];
    #pragma unroll
    for (int mt = 0; mt < 2; mt++)
        #pragma unroll
        for (int jj = 0; jj < 2; jj++)
            acc[mt][jj] = (floatx4){0.f, 0.f, 0.f, 0.f};

    const short8* Bf = (const short8*)WtF;
    #pragma unroll
    for (int kt = 0; kt < 8; kt++) {
        int ch = (kt * 4 + quad) ^ (half & 7);     // same swizzle for both A rows
        short8 a0 = *((const short8*)&a_s[half * 256 + ch * 8]);
        short8 a1 = *((const short8*)&a_s[(16 + half) * 256 + ch * 8]);
        #pragma unroll
        for (int jj = 0; jj < 2; jj++) {
            int j = wv * 2 + jj;
            short8 b = Bf[(j * 8 + kt) * 64 + lane];
            acc[0][jj] = __builtin_amdgcn_mfma_f32_16x16x32_bf16(a0, b, acc[0][jj], 0, 0, 0);
            acc[1][jj] = __builtin_amdgcn_mfma_f32_16x16x32_bf16(a1, b, acc[1][jj], 0, 0, 0);
        }
    }

    if (!LAST) {
        #pragma unroll
        for (int jj = 0; jj < 2; jj++) {
            int col = (wv * 2 + jj) * 16 + half;
            float bv = bias[col];
            #pragma unroll
            for (int mt = 0; mt < 2; mt++)
                #pragma unroll
                for (int r = 0; r < 4; r++)
                    c_s[mt * 16 + quad * 4 + r][col] = f2bf(fmaxf(acc[mt][jj][r] + bv, 0.f));
        }
        __syncthreads();
        #pragma unroll
        for (int it = 0; it < 2; ++it) {
            int t = it * 256 + tid;
            int rl = t >> 4;
            int c = t & 15;
            int row = m0 + rl;
            if (row < N_NODES)
                *((uint4*)(hout + (size_t)row * D + c * 8)) = *((const uint4*)&c_s[rl][c * 8]);
        }
    } else {
        float* red = (float*)&c_s[0][0];           // [32][4] floats, aliases c_s
        float vout[2][4] = {{0.f, 0.f, 0.f, 0.f}, {0.f, 0.f, 0.f, 0.f}};
        #pragma unroll
        for (int jj = 0; jj < 2; jj++) {
            int col = (wv * 2 + jj) * 16 + half;
            float bv = bias[col];
            float wo = Wout[col];
            #pragma unroll
            for (int mt = 0; mt < 2; mt++)
                #pragma unroll
                for (int r = 0; r < 4; r++)
                    vout[mt][r] += fmaxf(acc[mt][jj][r] + bv, 0.f) * wo;
        }
        #pragma unroll
        for (int off = 1; off < 16; off <<= 1) {
            #pragma unroll
            for (int mt = 0; mt < 2; mt++)
                #pragma unroll
                for (int r = 0; r < 4; r++)
                    vout[mt][r] += __shfl_xor(vout[mt][r], off, 64);
        }
        if (half == 0) {
            #pragma unroll
            for (int mt = 0; mt < 2; mt++)
                #pragma unroll
                for (int r = 0; r < 4; r++)
                    red[(mt * 16 + quad * 4 + r) * 4 + wv] = vout[mt][r];
        }
        __syncthreads();
        if (tid < 32) {
            int row = m0 + tid;
            if (row < N_NODES)
                out[row] = red[tid * 4 + 0] + red[tid * 4 + 1] +
                           red[tid * 4 + 2] + red[tid * 4 + 3] + bout[0];
        }
    }
}

// ---------------- launch ----------------

extern "C" void kernel_launch(void* const* d_in, const int* in_sizes, int n_in,
                              void* d_out, int out_size, void* d_ws, size_t ws_size,
                              hipStream_t stream) {
    const float* x     = (const float*)d_in[0];
    const int*   edge  = (const int*)d_in[1];   // [2, E]: src then dst
    const float* W_l   = (const float*)d_in[2];
    const float* b_l   = (const float*)d_in[3];
    const float* W_r   = (const float*)d_in[4];
    const float* W_out = (const float*)d_in[5];
    const float* b_out = (const float*)d_in[6];
    float* out = (float*)d_out;

    char* ws = (char*)d_ws;
    size_t off = 0;
    auto alloc = [&](size_t bytes) -> void* {
        void* p = ws + off;
        off += (bytes + 255) & ~(size_t)255;
        return p;
    };
    unsigned short* xb  = (unsigned short*)alloc((size_t)(N_NODES + 1) * D * 2);
    unsigned short* hb1 = (unsigned short*)alloc((size_t)(N_NODES + 1) * D * 2);
    unsigned short* hb2 = (unsigned short*)alloc((size_t)(N_NODES + 1) * D * 2);
    unsigned short* WtF = (unsigned short*)alloc((size_t)NLAYERS * D * 256 * 2);
    int*   deg       = (int*)alloc((size_t)N_NODES * sizeof(int));
    int*   row_start = (int*)alloc((size_t)N_NODES * sizeof(int));
    int*   cursor    = (int*)alloc((size_t)N_NODES * sizeof(int));
    float* inv_deg   = (float*)alloc((size_t)N_NODES * sizeof(float));
    int*   csr_src   = (int*)alloc((size_t)CSR_CAP * sizeof(int));
    int*   counter   = (int*)alloc(256);

    const int* src = edge;
    const int* dst = edge + N_EDGES;

    cvt_init_kernel<<<(CVT_TOTAL + 255) / 256, 256, 0, stream>>>(
        x, W_l, W_r, xb, hb1, hb2, WtF, deg, cursor, counter);
    hist_kernel<<<(N_EDGES + 255) / 256, 256, 0, stream>>>(dst, deg);
    alloc_kernel<<<(N_NODES + 255) / 256, 256, 0, stream>>>(deg, counter, row_start, inv_deg, csr_src);
    fill_kernel<<<(N_EDGES + 255) / 256, 256, 0, stream>>>(src, dst, row_start, cursor, csr_src);

    const int grid = (N_NODES + 31) / 32;

    // layer 0: xb -> hb1
    fused_layer_kernel<false><<<grid, 256, 0, stream>>>(
        xb, row_start, deg, csr_src, inv_deg, WtF, b_l, hb1, W_out, b_out, out);
    // layer 1: hb1 -> hb2 (ping-pong: fused blocks write while others gather)
    fused_layer_kernel<false><<<grid, 256, 0, stream>>>(
        hb1, row_start, deg, csr_src, inv_deg, WtF + (size_t)1 * D * 256, b_l + 1 * D,
        hb2, W_out, b_out, out);
    // layer 2: hb2 -> out (fused readout)
    fused_layer_kernel<true><<<grid, 256, 0, stream>>>(
        hb2, row_start, deg, csr_src, inv_deg, WtF + (size_t)2 * D * 256, b_l + 2 * D,
        hb1, W_out, b_out, out);
}